// Round 3
// baseline (435.007 us; speedup 1.0000x reference)
//
#include <hip/hip_runtime.h>
#include <stdint.h>

#define B_N 4096
#define T_N 17
#define C_N 512

typedef __bf16 bf16x8 __attribute__((ext_vector_type(8)));
typedef float  f32x4  __attribute__((ext_vector_type(4)));

// fp32 -> bf16 round-to-nearest-even (finite values)
__device__ __forceinline__ unsigned short f2b(float f){
  unsigned u = __float_as_uint(f);
  return (unsigned short)((u + 0x7fffu + ((u >> 16) & 1u)) >> 16);
}
__device__ __forceinline__ unsigned pk2(float a, float b){
  return (unsigned)f2b(a) | ((unsigned)f2b(b) << 16);
}

// async global->LDS, 16B/lane; LDS dest = wave-uniform base + lane*16
// (chunk = r*256+tid is lane-consecutive within each wave)
__device__ __forceinline__ void gll16(const void* g, void* l){
  __builtin_amdgcn_global_load_lds(
      (const __attribute__((address_space(1))) unsigned int*)g,
      (__attribute__((address_space(3))) unsigned int*)l, 16, 0, 0);
}

// ---------------------------------------------------------------------------
// prep (single launch, block-range dispatch):
//   blocks [0,2176):      wsb = bf16(Ws), dwb = bf16(Wt-Ws)
//   blocks [2176,2210):   bsum = bs + bt (fp32)
//   blocks [2210,3234):   x-scan: xb = bf16(x) (if mat), u/v fp32 planes:
//     u = (S + 18*x0 + 2*x16)/37, v = (x16-x0)/37, S = sum_t x[b,t,c]
//   x-part thread mapping: b = idx>>6, lane l = idx&63 handles channels
//   [4l,4l+4) and [256+4l,256+4l+4) -> every load/store instruction is a
//   fully-contiguous 1KB (fp32) / 512B (bf16) wave segment.
// ---------------------------------------------------------------------------
__global__ __launch_bounds__(256) void prep(
    const float* __restrict__ x,
    const float* __restrict__ Ws, const float* __restrict__ Wt,
    const float* __restrict__ bs, const float* __restrict__ bt,
    unsigned short* __restrict__ xb,
    float* __restrict__ u, float* __restrict__ v,
    unsigned short* __restrict__ wsb, unsigned short* __restrict__ dwb,
    float* __restrict__ bsum, int mat)
{
  const int bid = blockIdx.x;
  if (bid < 2176){
    const size_t i8 = ((size_t)bid * 256 + threadIdx.x) * 8;
    float4 a0 = *(const float4*)(Ws + i8);
    float4 a1 = *(const float4*)(Ws + i8 + 4);
    float4 b0 = *(const float4*)(Wt + i8);
    float4 b1 = *(const float4*)(Wt + i8 + 4);
    uint4 oa, od;
    oa.x = pk2(a0.x, a0.y); oa.y = pk2(a0.z, a0.w);
    oa.z = pk2(a1.x, a1.y); oa.w = pk2(a1.z, a1.w);
    od.x = pk2(b0.x - a0.x, b0.y - a0.y); od.y = pk2(b0.z - a0.z, b0.w - a0.w);
    od.z = pk2(b1.x - a1.x, b1.y - a1.y); od.w = pk2(b1.z - a1.z, b1.w - a1.w);
    *(uint4*)(wsb + i8) = oa;
    *(uint4*)(dwb + i8) = od;
  } else if (bid < 2210){
    const int i = (bid - 2176) * 256 + threadIdx.x;   // 8704 total
    if (i < T_N * C_N) bsum[i] = bs[i] + bt[i];
  } else {
    const int idx = (bid - 2210) * 256 + threadIdx.x; // 262144
    const int b = idx >> 6;
    const int l = idx & 63;
    const int c0 = 4 * l;          // 0..252
    const int c1 = 256 + 4 * l;    // 256..508
    const float* xp = x + (size_t)b * (T_N * C_N);
    float s[8] = {0,0,0,0,0,0,0,0};
    float f0[8], fl[8];
#pragma unroll
    for (int tt = 0; tt < T_N; ++tt){
      float4 w0 = *(const float4*)(xp + (size_t)tt * C_N + c0);
      float4 w1 = *(const float4*)(xp + (size_t)tt * C_N + c1);
      float f[8] = {w0.x, w0.y, w0.z, w0.w, w1.x, w1.y, w1.z, w1.w};
      if (mat){
        unsigned short* xo = xb + ((size_t)b * T_N + tt) * C_N;
        uint2 p0, p1;
        p0.x = pk2(f[0], f[1]); p0.y = pk2(f[2], f[3]);
        p1.x = pk2(f[4], f[5]); p1.y = pk2(f[6], f[7]);
        *(uint2*)(xo + c0) = p0;
        *(uint2*)(xo + c1) = p1;
      }
      if (tt == 0){
#pragma unroll
        for (int i2=0;i2<8;++i2) f0[i2] = f[i2];
      }
      if (tt == T_N-1){
#pragma unroll
        for (int i2=0;i2<8;++i2) fl[i2] = f[i2];
      }
#pragma unroll
      for (int i2=0;i2<8;++i2) s[i2] += f[i2];
    }
    const float inv = 1.0f / 37.0f;
    float uu[8], vv[8];
#pragma unroll
    for (int i2=0;i2<8;++i2){
      uu[i2] = (s[i2] + 18.0f * f0[i2] + 2.0f * fl[i2]) * inv;
      vv[i2] = (fl[i2] - f0[i2]) * inv;
    }
    float* up = u + (size_t)b * C_N;
    float* vp = v + (size_t)b * C_N;
    *(float4*)(up + c0) = make_float4(uu[0], uu[1], uu[2], uu[3]);
    *(float4*)(up + c1) = make_float4(uu[4], uu[5], uu[6], uu[7]);
    *(float4*)(vp + c0) = make_float4(vv[0], vv[1], vv[2], vv[3]);
    *(float4*)(vp + c1) = make_float4(vv[4], vv[5], vv[6], vv[7]);
  }
}

// ---------------------------------------------------------------------------
// gemm: per token t, out[:,t,:] = [x | u + t*v]_bf16 (M=4096 x K=1024) *
//       [Ws | dW]_bf16^T + bsum, fp32 accumulate/store.
// 128x128 tile, BK=32, 4 waves, 4x4 frags of mfma_f32_16x16x32_bf16.
// LDS tiles [128 rows][32 k]; 16B chunks XOR-swizzled: slot s of row r holds
// global chunk s ^ ((r>>1)&3) -> free 2-way bank aliasing on ds_read_b128
// (verified: SQ_LDS_BANK_CONFLICT = 0 in round 2).
// A-staging: k<512 gll16 from xb (MAT) / fp32-convert (!MAT);
//            k>=512 trend = u + t*v computed in VGPRs from fp32 planes
//            (u,v are t-independent -> L2/L3-hot for all 17 t).
// ---------------------------------------------------------------------------
template<bool MAT>
__global__ __launch_bounds__(256) void gemm_k(
    const float* __restrict__ x,            // fp32 x (!MAT staging)
    const unsigned short* __restrict__ xb,  // bf16 x (MAT staging)
    const unsigned short* __restrict__ wsb,
    const unsigned short* __restrict__ dwb,
    const float* __restrict__ u,
    const float* __restrict__ v,
    const float* __restrict__ bsum,
    float* __restrict__ out)
{
  __shared__ alignas(16) unsigned short As[128*32];
  __shared__ alignas(16) unsigned short Bs[128*32];

  const int tid  = threadIdx.x;
  const int bx   = blockIdx.x;          // t*128 + mt*4 + nt
  const int nt   = bx & 3;
  const int mt   = (bx >> 2) & 31;
  const int t    = bx >> 7;
  const int m0   = mt << 7;
  const int n0   = nt << 7;
  const int lane = tid & 63;
  const int wave = tid >> 6;
  const int wm   = (wave >> 1) << 6;
  const int wn   = (wave & 1) << 6;
  const int lr   = lane & 15;
  const int lj   = lane >> 4;
  const int swz  = (lr >> 1) & 3;

  f32x4 acc[4][4];
#pragma unroll
  for (int i=0;i<4;++i)
#pragma unroll
    for (int j=0;j<4;++j){ f32x4 z = {0.f,0.f,0.f,0.f}; acc[i][j] = z; }

  const float tf = (float)t;

  for (int kk = 0; kk < 32; ++kk){
    const int k0 = kk << 5;
    __syncthreads();
    // ---- stage A tile (rows = batch) ----
    if (k0 < 512){
      if (MAT){
#pragma unroll
        for (int r = 0; r < 2; ++r){
          const int chunk = r*256 + tid;
          const int row = chunk >> 2;
          const int cgl = (chunk & 3) ^ ((row >> 1) & 3);
          gll16(xb + ((size_t)(m0+row)*T_N + t)*C_N + k0 + cgl*8, &As[chunk*8]);
        }
      } else {
#pragma unroll
        for (int r = 0; r < 2; ++r){
          const int chunk = r*256 + tid;
          const int row = chunk >> 2;
          const int cgl = (chunk & 3) ^ ((row >> 1) & 3);
          const float* g = x + ((size_t)(m0+row)*T_N + t)*C_N + k0 + cgl*8;
          float4 w0 = *(const float4*)g;
          float4 w1 = *(const float4*)(g + 4);
          uint4 o;
          o.x = pk2(w0.x, w0.y); o.y = pk2(w0.z, w0.w);
          o.z = pk2(w1.x, w1.y); o.w = pk2(w1.z, w1.w);
          *(uint4*)&As[chunk*8] = o;
        }
      }
    } else {
      // trend = u + t*v from fp32 planes (t-independent, cache-hot)
#pragma unroll
      for (int r = 0; r < 2; ++r){
        const int chunk = r*256 + tid;
        const int row = chunk >> 2;
        const int cgl = (chunk & 3) ^ ((row >> 1) & 3);
        const size_t go = (size_t)(m0+row)*C_N + (k0 - 512) + cgl*8;
        float4 u0 = *(const float4*)(u + go);
        float4 u1 = *(const float4*)(u + go + 4);
        float4 v0 = *(const float4*)(v + go);
        float4 v1 = *(const float4*)(v + go + 4);
        uint4 o;
        o.x = pk2(fmaf(tf, v0.x, u0.x), fmaf(tf, v0.y, u0.y));
        o.y = pk2(fmaf(tf, v0.z, u0.z), fmaf(tf, v0.w, u0.w));
        o.z = pk2(fmaf(tf, v1.x, u1.x), fmaf(tf, v1.y, u1.y));
        o.w = pk2(fmaf(tf, v1.z, u1.z), fmaf(tf, v1.w, u1.w));
        *(uint4*)&As[chunk*8] = o;
      }
    }
    // ---- stage B tile (rows = output channel d) ----
#pragma unroll
    for (int r = 0; r < 2; ++r){
      const int chunk = r*256 + tid;
      const int row = chunk >> 2;
      const int cgl = (chunk & 3) ^ ((row >> 1) & 3);
      const unsigned short* g = (k0 < 512)
        ? wsb + ((size_t)t*C_N + n0 + row)*C_N + k0 + cgl*8
        : dwb + ((size_t)t*C_N + n0 + row)*C_N + (k0 - 512) + cgl*8;
      gll16(g, &Bs[chunk*8]);
    }
    __syncthreads();

    bf16x8 af[4], bf[4];
#pragma unroll
    for (int i=0;i<4;++i){
      const int row = wm + i*16 + lr;
      af[i] = *(const bf16x8*)&As[row*32 + ((lj ^ swz) * 8)];
    }
#pragma unroll
    for (int i=0;i<4;++i){
      const int row = wn + i*16 + lr;
      bf[i] = *(const bf16x8*)&Bs[row*32 + ((lj ^ swz) * 8)];
    }
#pragma unroll
    for (int mi=0;mi<4;++mi)
#pragma unroll
      for (int ni=0;ni<4;++ni)
        acc[mi][ni] = __builtin_amdgcn_mfma_f32_16x16x32_bf16(af[mi], bf[ni], acc[mi][ni], 0, 0, 0);
  }

  // ---- epilogue. C/D layout: col=lane&15, row=(lane>>4)*4+reg ----
  float bias[4];
#pragma unroll
  for (int ni=0;ni<4;++ni)
    bias[ni] = bsum[(size_t)t*C_N + n0 + wn + ni*16 + lr];

#pragma unroll
  for (int mi=0;mi<4;++mi){
#pragma unroll
    for (int r=0;r<4;++r){
      const int m = m0 + wm + mi*16 + lj*4 + r;
      float* op = out + ((size_t)m*T_N + t)*C_N + n0 + wn + lr;
#pragma unroll
      for (int ni=0;ni<4;++ni)
        op[ni*16] = acc[mi][ni][r] + bias[ni];
    }
  }
}

extern "C" void kernel_launch(void* const* d_in, const int* in_sizes, int n_in,
                              void* d_out, int out_size, void* d_ws, size_t ws_size,
                              hipStream_t stream)
{
  const float* x   = (const float*)d_in[0];
  const float* Wsl = (const float*)d_in[1];
  const float* bsl = (const float*)d_in[2];
  const float* Wtr = (const float*)d_in[3];
  const float* btr = (const float*)d_in[4];
  float* out = (float*)d_out;

  const size_t WSB_BYTES = (size_t)T_N*C_N*C_N*2;  //  8,912,896
  const size_t DW_BYTES  = WSB_BYTES;              //  8,912,896
  const size_t BS_BYTES  = (size_t)T_N*C_N*4;      //     34,816
  const size_t U_BYTES   = (size_t)B_N*C_N*4;      //  8,388,608
  const size_t V_BYTES   = U_BYTES;                //  8,388,608
  const size_t XB_BYTES  = (size_t)B_N*T_N*C_N*2;  // 71,303,168

  char* ws = (char*)d_ws;
  unsigned short* wsb  = (unsigned short*)ws;
  unsigned short* dwb  = (unsigned short*)(ws + WSB_BYTES);
  float*          bsum = (float*)(ws + WSB_BYTES + DW_BYTES);
  float*          u    = (float*)(ws + WSB_BYTES + DW_BYTES + BS_BYTES);
  float*          v    = (float*)(ws + WSB_BYTES + DW_BYTES + BS_BYTES + U_BYTES);
  unsigned short* xb   = (unsigned short*)(ws + WSB_BYTES + DW_BYTES + BS_BYTES + U_BYTES + V_BYTES);
  // fixed per run (ws_size constant) -> graph-capture safe
  const bool mat = ws_size >= WSB_BYTES + DW_BYTES + BS_BYTES + U_BYTES + V_BYTES + XB_BYTES;

  prep<<<dim3(3234), dim3(256), 0, stream>>>(x, Wsl, Wtr, bsl, btr,
                                             xb, u, v, wsb, dwb, bsum, mat ? 1 : 0);
  if (mat)
    gemm_k<true><<<dim3(2176), dim3(256), 0, stream>>>(x, xb, wsb, dwb, u, v, bsum, out);
  else
    gemm_k<false><<<dim3(2176), dim3(256), 0, stream>>>(x, nullptr, wsb, dwb, u, v, bsum, out);
  (void)in_sizes; (void)n_in; (void)out_size;
}